// Round 8
// baseline (295.987 us; speedup 1.0000x reference)
//
#include <hip/hip_runtime.h>

typedef unsigned short u16;
typedef short bf16x8 __attribute__((ext_vector_type(8)));
typedef float f32x4 __attribute__((ext_vector_type(4)));
typedef u16 u16x4 __attribute__((ext_vector_type(4)));

#define GRID_BLOCKS 512

__device__ __forceinline__ float b2f(u16 h) {
  unsigned u = ((unsigned)h) << 16;
  return __builtin_bit_cast(float, u);
}
__device__ __forceinline__ u16 f2b(float f) {
  unsigned u = __builtin_bit_cast(unsigned, f);
  u = u + 0x7fffu + ((u >> 16) & 1u);   // round-to-nearest-even
  return (u16)(u >> 16);
}

#if defined(__has_builtin)
#if __has_builtin(__builtin_amdgcn_cvt_pk_bf16_f32)
#define HAVE_CVT_PK_BF16 1
#endif
#endif

__device__ __forceinline__ unsigned f2b_pk(float a, float b) {
#ifdef HAVE_CVT_PK_BF16
  auto v = __builtin_amdgcn_cvt_pk_bf16_f32(a, b);
  unsigned r;
  __builtin_memcpy(&r, &v, 4);
  return r;
#else
  return (unsigned)f2b(a) | (((unsigned)f2b(b)) << 16);
#endif
}
__device__ __forceinline__ bf16x8 pack8(const float* v) {
  union { unsigned u[4]; bf16x8 o; } r;
  r.u[0] = f2b_pk(v[0], v[1]);
  r.u[1] = f2b_pk(v[2], v[3]);
  r.u[2] = f2b_pk(v[4], v[5]);
  r.u[3] = f2b_pk(v[6], v[7]);
  return r.o;
}
__device__ __forceinline__ u16x4 pack4(float a, float b, float c, float d) {
  union { unsigned u[2]; u16x4 o; } r;
  r.u[0] = f2b_pk(a, b);
  r.u[1] = f2b_pk(c, d);
  return r.o;
}

// ---------------------------------------------------------------------------
// Fused single-dispatch kernel.
// Phase 0: blocks [0,128)  -> pre-chain (16 nodes each) writing flat bf16
//          blocks [128,192)-> post_w fp32 -> bf16 staged [s8(32)][m(256)][8]
// grid barrier (device-scope atomics; 512 blocks == exact 2/CU capacity,
// guaranteed by launch_bounds(256,2) + 66 KB LDS)
// Phase 1: every block: 4 tiles of (build XX -> GEMM1 -> T1 -> GEMM2 -> W3)
// ---------------------------------------------------------------------------
__global__ __launch_bounds__(256, 2) void dense_edge_fused(
    const float* __restrict__ x, const int* __restrict__ pidx,
    const int* __restrict__ cidx, const float* __restrict__ pre_w,
    const float* __restrict__ preb, const float* __restrict__ post_w,
    const float* __restrict__ postb, const float* __restrict__ w3,
    const float* __restrict__ b3, float* __restrict__ out,
    int* __restrict__ ctr, u16* __restrict__ w1s, u16* __restrict__ w2s,
    u16* __restrict__ flat) {
  __shared__ union {
    struct { float xtile[256 * 20]; u16 feat[2][4096]; } pre;      // 36,864 B
    struct { u16 xxbuf[16384]; u16 t1buf[16384]; float pbuf[4][2][64]; } mn;  // 67,584 B
  } sm;

  const int blk = blockIdx.x;
  const int t = threadIdx.x;
  const int wv = t >> 6, ln = t & 63;
  const int q4 = ln >> 4, r15 = ln & 15;

  // =========================== phase 0 ===========================
  if (blk >= 128 && blk < 192) {
    // ---- post-weight staging ----
    const int id = (blk - 128) * 256 + t;   // 16384 slots of 8 elems
    const int layer = id >> 13;             // 0..1
    const int sid = id & 8191;
    const int m = sid >> 5;
    const int s8 = sid & 31;
    const float* src = post_w + layer * 65536 + m * 256 + s8 * 8;
    u16* dst = layer ? w2s : w1s;
    f32x4 a = *(const f32x4*)(src);
    f32x4 c = *(const f32x4*)(src + 4);
    float tmp[8] = {a[0], a[1], a[2], a[3], c[0], c[1], c[2], c[3]};
    *(bf16x8*)(dst + (s8 * 256 + m) * 8) = pack8(tmp);
  } else if (blk < 128) {
    // ---- pre-chain for nodes [blk*16, blk*16+16) ----
    const int nb = blk * 16;
    const int b0 = nb >> 10;
    const int hw0 = nb & 1023;
    {  // x slice: thread t = channel, 16 nodes
      const float* src = x + (b0 * 256 + t) * 1024 + hw0;
      f32x4 v0 = *(const f32x4*)(src);
      f32x4 v1 = *(const f32x4*)(src + 4);
      f32x4 v2 = *(const f32x4*)(src + 8);
      f32x4 v3 = *(const f32x4*)(src + 12);
      *(f32x4*)&sm.pre.xtile[t * 20 + 0] = v0;
      *(f32x4*)&sm.pre.xtile[t * 20 + 4] = v1;
      *(f32x4*)&sm.pre.xtile[t * 20 + 8] = v2;
      *(f32x4*)&sm.pre.xtile[t * 20 + 12] = v3;
    }
    __syncthreads();
#pragma unroll
    for (int rep = 0; rep < 2; rep++) {
      const int id = rep * 256 + t;
      const int n = id & 15, s8 = id >> 4;
      float tmp[8];
#pragma unroll
      for (int j = 0; j < 8; j++) tmp[j] = sm.pre.xtile[(s8 * 8 + j) * 20 + n];
      *(bf16x8*)(&sm.pre.feat[0][(s8 * 16 + n) * 8]) = pack8(tmp);
    }
    __syncthreads();
#pragma unroll
    for (int l = 0; l < 3; l++) {
      const float* wl = pre_w + l * 65536;
      f32x4 acc[4];
      f32x4 zero = {0.f, 0.f, 0.f, 0.f};
#pragma unroll
      for (int mt = 0; mt < 4; mt++) acc[mt] = zero;
#pragma unroll
      for (int s = 0; s < 8; s++) {
        bf16x8 bv = *(const bf16x8*)(&sm.pre.feat[l & 1][((s * 4 + q4) * 16 + r15) * 8]);
#pragma unroll
        for (int mt = 0; mt < 4; mt++) {
          const float* wp = wl + (wv * 64 + mt * 16 + r15) * 256 + (s * 4 + q4) * 8;
          f32x4 wa = *(const f32x4*)(wp);
          f32x4 wc = *(const f32x4*)(wp + 4);
          float tmp[8] = {wa[0], wa[1], wa[2], wa[3], wc[0], wc[1], wc[2], wc[3]};
          bf16x8 av = pack8(tmp);
          acc[mt] = __builtin_amdgcn_mfma_f32_16x16x32_bf16(av, bv, acc[mt], 0, 0, 0);
        }
      }
      if (l < 2) {
#pragma unroll
        for (int mt = 0; mt < 4; mt++) {
          const int o = wv * 64 + mt * 16 + q4 * 4;
          f32x4 bb = *(const f32x4*)(preb + l * 256 + o);
          *(u16x4*)(&sm.pre.feat[(l + 1) & 1][((o >> 3) * 16 + r15) * 8 + (o & 7)]) =
              pack4(fmaxf(acc[mt][0] + bb[0], 0.f), fmaxf(acc[mt][1] + bb[1], 0.f),
                    fmaxf(acc[mt][2] + bb[2], 0.f), fmaxf(acc[mt][3] + bb[3], 0.f));
        }
        __syncthreads();
      } else {
#pragma unroll
        for (int mt = 0; mt < 4; mt++) {
          const int o = wv * 64 + mt * 16 + q4 * 4;
          f32x4 bb = *(const f32x4*)(preb + 512 + o);
          *(u16x4*)(flat + (nb + r15) * 256 + o) =
              pack4(acc[mt][0] + bb[0], acc[mt][1] + bb[1],
                    acc[mt][2] + bb[2], acc[mt][3] + bb[3]);   // no relu
        }
      }
    }
  }

  // =========================== grid barrier ===========================
  __syncthreads();
  if (t == 0) {
    __threadfence();                 // release this block's global writes
    atomicAdd(ctr, 1);               // device-scope
    while (atomicAdd(ctr, 0) < GRID_BLOCKS) __builtin_amdgcn_s_sleep(8);
  }
  __syncthreads();
  __threadfence();                   // acquire: invalidate stale L1/L2 lines

  // =========================== phase 1 ===========================
  const int tile0 = blk * 4;
  const int b = tile0 >> 10;
  const int pt = (tile0 >> 5) & 31;  // constant across the 4 tiles
  const int p0 = pt * 8;
  const int pn = pidx[b * 256 + p0 + (ln >> 3)];
  const u16* prow = flat + pn * 256 + wv * 64;

#pragma unroll 1
  for (int i = 0; i < 4; i++) {
    const int qt = (tile0 + i) & 31;
    const int q0 = qt * 8;

    // W1 fragments into regs (overlaps gather latency)
    bf16x8 af_w[4][8];
#pragma unroll
    for (int s = 0; s < 8; s++)
#pragma unroll
      for (int mt = 0; mt < 4; mt++)
        af_w[mt][s] = *(const bf16x8*)(w1s + ((s * 4 + q4) * 256 + wv * 64 + mt * 16 + r15) * 8);

    // build XX: lane = pair n = ln, c-block = wv
    {
      const int qn = cidx[b * 256 + q0 + (ln & 7)];
      const u16* qrow = flat + qn * 256 + wv * 64;
#pragma unroll
      for (int ii = 0; ii < 8; ii++) {
        bf16x8 av = *(const bf16x8*)(prow + ii * 8);
        bf16x8 bv = *(const bf16x8*)(qrow + ii * 8);
        float d[8];
#pragma unroll
        for (int jj = 0; jj < 8; jj++) {
          float dv = b2f((u16)av[jj]) - b2f((u16)bv[jj]);
          d[jj] = dv * dv;
        }
        *(bf16x8*)(sm.mn.xxbuf + ((wv * 8 + ii) * 64 + ln) * 8) = pack8(d);
      }
    }
    __syncthreads();   // XX visible

    // ---- GEMM1 ----
    f32x4 acc[4][4];
    {
      f32x4 zero = {0.f, 0.f, 0.f, 0.f};
#pragma unroll
      for (int mt = 0; mt < 4; mt++)
#pragma unroll
        for (int nt = 0; nt < 4; nt++) acc[mt][nt] = zero;
    }
#pragma unroll
    for (int s = 0; s < 8; s++) {
      bf16x8 bfr[4];
#pragma unroll
      for (int nt = 0; nt < 4; nt++)
        bfr[nt] = *(const bf16x8*)(sm.mn.xxbuf + ((s * 4 + q4) * 64 + nt * 16 + r15) * 8);
#pragma unroll
      for (int mt = 0; mt < 4; mt++)
#pragma unroll
        for (int nt = 0; nt < 4; nt++)
          acc[mt][nt] = __builtin_amdgcn_mfma_f32_16x16x32_bf16(af_w[mt][s], bfr[nt], acc[mt][nt], 0, 0, 0);
    }

    // T1 writeback (relu + b1) + reload af_w with W2
#pragma unroll
    for (int mt = 0; mt < 4; mt++) {
      const int o = wv * 64 + mt * 16 + q4 * 4;
      f32x4 bb = *(const f32x4*)(postb + o);
#pragma unroll
      for (int nt = 0; nt < 4; nt++) {
        const int nn = nt * 16 + r15;
        *(u16x4*)(sm.mn.t1buf + ((o >> 3) * 64 + nn) * 8 + (o & 7)) =
            pack4(fmaxf(acc[mt][nt][0] + bb[0], 0.f),
                  fmaxf(acc[mt][nt][1] + bb[1], 0.f),
                  fmaxf(acc[mt][nt][2] + bb[2], 0.f),
                  fmaxf(acc[mt][nt][3] + bb[3], 0.f));
        acc[mt][nt][0] = 0.f; acc[mt][nt][1] = 0.f;
        acc[mt][nt][2] = 0.f; acc[mt][nt][3] = 0.f;
      }
    }
#pragma unroll
    for (int s = 0; s < 8; s++)
#pragma unroll
      for (int mt = 0; mt < 4; mt++)
        af_w[mt][s] = *(const bf16x8*)(w2s + ((s * 4 + q4) * 256 + wv * 64 + mt * 16 + r15) * 8);
    __syncthreads();   // T1 visible

    // ---- GEMM2 ----
#pragma unroll
    for (int s = 0; s < 8; s++) {
      bf16x8 bfr[4];
#pragma unroll
      for (int nt = 0; nt < 4; nt++)
        bfr[nt] = *(const bf16x8*)(sm.mn.t1buf + ((s * 4 + q4) * 64 + nt * 16 + r15) * 8);
#pragma unroll
      for (int mt = 0; mt < 4; mt++)
#pragma unroll
        for (int nt = 0; nt < 4; nt++)
          acc[mt][nt] = __builtin_amdgcn_mfma_f32_16x16x32_bf16(af_w[mt][s], bfr[nt], acc[mt][nt], 0, 0, 0);
    }

    // W3 register epilogue
    {
      float part[2][4] = {{0.f, 0.f, 0.f, 0.f}, {0.f, 0.f, 0.f, 0.f}};
#pragma unroll
      for (int mt = 0; mt < 4; mt++) {
        const int o = wv * 64 + mt * 16 + q4 * 4;
        f32x4 bb = *(const f32x4*)(postb + 256 + o);
        f32x4 w3a = *(const f32x4*)(w3 + o);
        f32x4 w3b = *(const f32x4*)(w3 + 256 + o);
#pragma unroll
        for (int nt = 0; nt < 4; nt++) {
#pragma unroll
          for (int r = 0; r < 4; r++) {
            float v = fmaxf(acc[mt][nt][r] + bb[r], 0.f);
            part[0][nt] += v * w3a[r];
            part[1][nt] += v * w3b[r];
          }
        }
      }
#pragma unroll
      for (int o3 = 0; o3 < 2; o3++)
#pragma unroll
        for (int nt = 0; nt < 4; nt++) {
          part[o3][nt] += __shfl_xor(part[o3][nt], 16, 64);
          part[o3][nt] += __shfl_xor(part[o3][nt], 32, 64);
        }
      if (q4 == 0) {
#pragma unroll
        for (int o3 = 0; o3 < 2; o3++)
#pragma unroll
          for (int nt = 0; nt < 4; nt++)
            sm.mn.pbuf[wv][o3][nt * 16 + r15] = part[o3][nt];
      }
    }
    __syncthreads();   // partials visible

    if (t < 128) {
      const int o3 = t >> 6;
      const int n = t & 63;
      float v = b3[o3] + sm.mn.pbuf[0][o3][n] + sm.mn.pbuf[1][o3][n] +
                sm.mn.pbuf[2][o3][n] + sm.mn.pbuf[3][o3][n];
      out[((b * 2 + o3) * 256 + p0 + (n >> 3)) * 256 + q0 + (n & 7)] = v;
    }
  }
}

// ---------------------------------------------------------------------------
extern "C" void kernel_launch(void* const* d_in, const int* in_sizes, int n_in,
                              void* d_out, int out_size, void* d_ws, size_t ws_size,
                              hipStream_t stream) {
  (void)in_sizes; (void)n_in; (void)out_size; (void)ws_size;
  const float* x          = (const float*)d_in[0];
  const int*   pidx       = (const int*)d_in[1];
  const int*   cidx       = (const int*)d_in[2];
  const float* pre_w      = (const float*)d_in[3];
  const float* pre_b      = (const float*)d_in[4];
  const float* post_w     = (const float*)d_in[5];
  const float* post_b     = (const float*)d_in[6];
  const float* post_out_w = (const float*)d_in[7];
  const float* post_out_b = (const float*)d_in[8];
  float* out = (float*)d_out;

  int* ctr  = (int*)d_ws;                 // barrier counter in [0,512)
  u16* base = (u16*)d_ws;
  u16* w1s  = base + 256;                 // staged post_w[0] bf16
  u16* w2s  = base + 256 + 65536;         // staged post_w[1] bf16
  u16* flat = base + 256 + 131072;        // node features bf16 [2048][256]

  hipMemsetAsync(d_ws, 0, 512, stream);   // zero barrier counter (graph-legal)
  dense_edge_fused<<<GRID_BLOCKS, 256, 0, stream>>>(
      x, pidx, cidx, pre_w, pre_b, post_w, post_b,
      post_out_w, post_out_b, out, ctr, w1s, w2s, flat);
}